// Round 1
// 167.660 us; speedup vs baseline: 1.0669x; 1.0669x over previous
//
#include <hip/hip_runtime.h>
#include <math.h>

// Problem constants (fixed by the reference setup_inputs): B=2, P=8192, K=16
#define PP    8192
#define NB    2
#define NPTS  16384          // NB * PP
#define KNN   16
#define EPSV  1e-17f

// ---- K1: brute-force exact 16-NN + phi + first denoise (fused) --------------
// 64 queries per block (one per lane), 8 waves; each wave scans a stride-8
// interleaved subset of the 8192 candidates from an LDS tile.
// Keys: d' = max(d,0); key = as_float((bits(d') & 0xFFFFE000) | idx).
// NEW vs previous version:
//  * Exact skip gate: insert chain runs only when
//      __any(key < min(keys[15], thr))
//    where thr is the exact 16th-smallest key of the union of all 8 wave
//    partials, refreshed at 3 checkpoints (1024/2048/4096 candidates seen).
//    Skipped candidates provably cannot be in the final top-16 set (only the
//    SET matters downstream — all K-slot uses are symmetric reductions).
//  * Partial-list merges use bitonic min-merge (16 min + 64 cmp-exch) instead
//    of 256 med3 per pair.
//  * denoise1 (phi + n1) fused into the tail: each wave finalizes 2 of the 16
//    slots (exact dist recompute, phi), d1 and n1 combined through LDS.

#define QPB   64
#define WPB   8
#define TPB   (WPB * 64)     // 512
#define TILE  TPB

#define KEY_BIG 3.0e38f      // > any real key, finite

// Merge two ascending sorted-16 lists, keep lowest 16, result ascending.
// c[i] = min(a[i], o[15-i]) is the lowest-16 multiset (bitonic); then a
// 4-stage bitonic cleaner sorts it.
__device__ __forceinline__ void merge16(float (&a)[KNN], const float (&o)[KNN]) {
    float c[KNN];
#pragma unroll
    for (int s = 0; s < KNN; ++s) c[s] = fminf(a[s], o[KNN - 1 - s]);
#pragma unroll
    for (int st = KNN / 2; st >= 1; st >>= 1) {
#pragma unroll
        for (int base = 0; base < KNN; base += 2 * st) {
#pragma unroll
            for (int k = 0; k < st; ++k) {
                const float x = c[base + k], y = c[base + k + st];
                c[base + k]      = fminf(x, y);
                c[base + k + st] = fmaxf(x, y);
            }
        }
    }
#pragma unroll
    for (int s = 0; s < KNN; ++s) a[s] = c[s];
}

__global__ __launch_bounds__(TPB, 2) void knn_fused_kernel(
        const float* __restrict__ pts,
        const float* __restrict__ normals,
        int*   __restrict__ out_idx,
        float* __restrict__ out_dist,
        float* __restrict__ out_phi,
        float* __restrict__ out_n1) {
    __shared__ float4 tile[TILE];                 // 8 KB (reused as mk at tail)
    __shared__ float  smerge[WPB * KNN * 64];     // 32 KB (reused for d1/n1)

    const int lane = threadIdx.x & 63;
    const int wave = threadIdx.x >> 6;
    const int q0   = blockIdx.x * QPB;            // global query base
    const int b    = q0 >> 13;                    // q0 / PP
    const int i    = (q0 & (PP - 1)) + lane;      // local query index
    const float* bp = pts     + (size_t)b * PP * 3;
    const float* bn = normals + (size_t)b * PP * 3;

    const float qx = bp[i * 3 + 0];
    const float qy = bp[i * 3 + 1];
    const float qz = bp[i * 3 + 2];
    const float d2q = qx * qx + qy * qy + qz * qz;

    float keys[KNN];
#pragma unroll
    for (int s = 0; s < KNN; ++s) keys[s] = KEY_BIG;
    float thr = KEY_BIG;                          // global-16th upper bound

    for (int t0 = 0; t0 < PP; t0 += TILE) {
        __syncthreads();
        {
            const int c = t0 + threadIdx.x;
            const float x = bp[c * 3 + 0];
            const float y = bp[c * 3 + 1];
            const float z = bp[c * 3 + 2];
            tile[threadIdx.x] = make_float4(x, y, z, x * x + y * y + z * z);
        }
        __syncthreads();

        for (int m = 0; m < TILE / WPB; m += 4) {
            float4 c4[4];
            float  key[4];
#pragma unroll
            for (int u = 0; u < 4; ++u) c4[u] = tile[wave + (m + u) * WPB];
#pragma unroll
            for (int u = 0; u < 4; ++u) {
                const int j = t0 + wave + (m + u) * WPB;
                const float dot = fmaf(qz, c4[u].z,
                                  fmaf(qy, c4[u].y, qx * c4[u].x));
                const float d  = fmaf(-2.0f, dot, d2q + c4[u].w);
                const float dc = fmaxf(d, 0.0f);
                unsigned int kb =
                    (__float_as_uint(dc) & 0xFFFFE000u) | (unsigned int)j;
                float k = __uint_as_float(kb);
                if (j == i) k = KEY_BIG;          // exclude self
                key[u] = k;
            }
#pragma unroll
            for (int u = 0; u < 4; ++u) {
                // Exact gate: if no lane's candidate can enter the FINAL
                // global top-16, the whole insert chain is skippable.
                if (__any(key[u] < fminf(keys[KNN - 1], thr))) {
#pragma unroll
                    for (int s = KNN - 1; s >= 1; --s)
                        keys[s] = __builtin_amdgcn_fmed3f(keys[s - 1], key[u], keys[s]);
                    keys[0] = fminf(keys[0], key[u]);
                }
            }
        }

        // Checkpoints after 1024 / 2048 / 4096 candidates seen block-wide:
        // thr := exact 16th-smallest of the union of all 8 wave partials.
        if (t0 == 512 || t0 == 1536 || t0 == 3584) {
            __syncthreads();
#pragma unroll
            for (int s = 0; s < KNN; ++s)
                smerge[(wave * KNN + s) * 64 + lane] = keys[s];
            __syncthreads();
            float mm[KNN];
#pragma unroll
            for (int s = 0; s < KNN; ++s) mm[s] = smerge[s * 64 + lane];
#pragma unroll
            for (int w = 1; w < WPB - 1; ++w) {
                float o[KNN];
#pragma unroll
                for (int s = 0; s < KNN; ++s)
                    o[s] = smerge[(w * KNN + s) * 64 + lane];
                merge16(mm, o);
            }
            {   // last list: only the max of the lowest-16 multiset is needed
                float o[KNN];
#pragma unroll
                for (int s = 0; s < KNN; ++s)
                    o[s] = smerge[((WPB - 1) * KNN + s) * 64 + lane];
                float t = fminf(mm[0], o[KNN - 1]);
#pragma unroll
                for (int s = 1; s < KNN; ++s)
                    t = fmaxf(t, fminf(mm[s], o[KNN - 1 - s]));
                thr = t;
            }
        }
    }

    // ---- final merge (wave 0, bitonic tree is unnecessary: 7 cheap merges) --
    __syncthreads();
#pragma unroll
    for (int s = 0; s < KNN; ++s)
        smerge[(wave * KNN + s) * 64 + lane] = keys[s];
    __syncthreads();
    float* mk = (float*)tile;                     // 16*64 floats, tile is dead
    if (wave == 0) {
        float mm[KNN];
#pragma unroll
        for (int s = 0; s < KNN; ++s) mm[s] = smerge[s * 64 + lane];
#pragma unroll
        for (int w = 1; w < WPB; ++w) {
            float o[KNN];
#pragma unroll
            for (int s = 0; s < KNN; ++s)
                o[s] = smerge[(w * KNN + s) * 64 + lane];
            if (w < WPB - 1) {
                merge16(mm, o);
            } else {        // last merge: set only, no sort needed
#pragma unroll
                for (int s = 0; s < KNN; ++s)
                    mm[s] = fminf(mm[s], o[KNN - 1 - s]);
            }
        }
#pragma unroll
        for (int s = 0; s < KNN; ++s) mk[s * 64 + lane] = mm[s];
    }
    __syncthreads();

    // ---- distributed tail: wave w finalizes slots (w, w+8) ------------------
    const int q  = q0 + lane;
    const int sA = wave, sB = wave + 8;
    const float kA = mk[sA * 64 + lane];
    const float kB = mk[sB * 64 + lane];
    const int jA = (int)(__float_as_uint(kA) & 0x1FFFu);
    const int jB = (int)(__float_as_uint(kB) & 0x1FFFu);

    // exact distances (same arithmetic as reference path)
    const float axp = bp[jA * 3 + 0], ayp = bp[jA * 3 + 1], azp = bp[jA * 3 + 2];
    const float bxp = bp[jB * 3 + 0], byp = bp[jB * 3 + 1], bzp = bp[jB * 3 + 2];
    const float dotA = qx * axp + qy * ayp + qz * azp;
    const float dotB = qx * bxp + qy * byp + qz * bzp;
    float dA = (d2q + (axp * axp + ayp * ayp + azp * azp)) - (dotA + dotA);
    float dB = (d2q + (bxp * bxp + byp * byp + bzp * bzp)) - (dotB + dotB);
    dA = fmaxf(dA, 0.0f);
    dB = fmaxf(dB, 0.0f);

    // d1 = min over all 16 slots, combined through LDS
    smerge[wave * 64 + lane] = fminf(dA, dB);
    __syncthreads();
    float d1 = smerge[lane];
#pragma unroll
    for (int w = 1; w < WPB; ++w) d1 = fminf(d1, smerge[w * 64 + lane]);

    const float s0v  = d1 * 8.0f;                 // 2 * FILTER_SCALE^2 = 8
    const float sden = (s0v < EPSV) ? EPSV : s0v; // _eps_denom
    const float wA = fmaxf(1.0f - dA / sden, 0.0f);
    const float wB = fmaxf(1.0f - dB / sden, 0.0f);
    const float phA = (wA * wA) * (wA * wA);
    const float phB = (wB * wB) * (wB * wB);

    out_idx [q * KNN + sA] = jA;  out_idx [q * KNN + sB] = jB;
    out_dist[q * KNN + sA] = dA;  out_dist[q * KNN + sB] = dB;
    out_phi [q * KNN + sA] = phA; out_phi [q * KNN + sB] = phB;

    // n1 partial (2 slots per wave), combined through LDS
    const float nax = bn[jA * 3 + 0], nay = bn[jA * 3 + 1], naz = bn[jA * 3 + 2];
    const float nbx = bn[jB * 3 + 0], nby = bn[jB * 3 + 1], nbz = bn[jB * 3 + 2];
    const float px = phA * nax + phB * nbx;
    const float py = phA * nay + phB * nby;
    const float pz = phA * naz + phB * nbz;
    const float ps = phA + phB;

    __syncthreads();                              // d1 reads done; reuse smerge
    smerge[(wave * 4 + 0) * 64 + lane] = px;
    smerge[(wave * 4 + 1) * 64 + lane] = py;
    smerge[(wave * 4 + 2) * 64 + lane] = pz;
    smerge[(wave * 4 + 3) * 64 + lane] = ps;
    __syncthreads();
    if (wave == 0) {
        float sx = 0.f, sy = 0.f, sz = 0.f, ss = 0.f;
#pragma unroll
        for (int w = 0; w < WPB; ++w) {
            sx += smerge[(w * 4 + 0) * 64 + lane];
            sy += smerge[(w * 4 + 1) * 64 + lane];
            sz += smerge[(w * 4 + 2) * 64 + lane];
            ss += smerge[(w * 4 + 3) * 64 + lane];
        }
        const float den = (ss < EPSV) ? EPSV : ss;
        out_n1[q * 3 + 0] = sx / den;
        out_n1[q * 3 + 1] = sy / den;
        out_n1[q * 3 + 2] = sz / den;
    }
}

// ---- K3: normal_w + second denoise (n2) -------------------------------------
__global__ void denoise2_kernel(const int* __restrict__ idx,
                                const float* __restrict__ phi,
                                const float* __restrict__ n1,
                                float* __restrict__ nw_out,
                                float* __restrict__ n2_out) {
    const int q = blockIdx.x * blockDim.x + threadIdx.x;
    if (q >= NPTS) return;
    const int b = q >> 13;
    const int gbase = b * PP;
    const float INV_SIG = 1.0f / (0.75f * 0.75f);

    const float ax = n1[q * 3 + 0];
    const float ay = n1[q * 3 + 1];
    const float az = n1[q * 3 + 2];
    const float an = fmaxf(sqrtf(ax * ax + ay * ay + az * az), 1e-12f);
    const float rx = ax / an, ry = ay / an, rz = az / an;

    float swn = 0.f, ox = 0.f, oy = 0.f, oz = 0.f;
#pragma unroll
    for (int s = 0; s < KNN; ++s) {
        const int j = idx[q * KNN + s];
        const float bx = n1[(gbase + j) * 3 + 0];
        const float by = n1[(gbase + j) * 3 + 1];
        const float bz = n1[(gbase + j) * 3 + 2];
        const float bnn = fmaxf(sqrtf(bx * bx + by * by + bz * bz), 1e-12f);
        const float ux = bx / bnn - rx;
        const float uy = by / bnn - ry;
        const float uz = bz / bnn - rz;
        const float dd = ux * ux + uy * uy + uz * uz;
        const float nw = expf(-dd * INV_SIG);
        nw_out[q * KNN + s] = nw;
        const float wk = phi[q * KNN + s] * nw;
        ox += wk * bx;                 // raw n1 (unnormalized), per reference
        oy += wk * by;
        oz += wk * bz;
        swn += wk;
    }
    const float den = (swn < EPSV) ? EPSV : swn;
    n2_out[q * 3 + 0] = ox / den;
    n2_out[q * 3 + 1] = oy / den;
    n2_out[q * 3 + 2] = oz / den;
}

// ---- K4: weights_proj + point-to-plane loss, per-block partial sums ---------
__global__ void loss_kernel(const float* __restrict__ pts,
                            const int* __restrict__ idx,
                            const float* __restrict__ dist,
                            const float* __restrict__ phi,
                            const float* __restrict__ nw,
                            const float* __restrict__ n2,
                            float* __restrict__ partial) {
    const int q = blockIdx.x * 64 + threadIdx.x;   // block = 64 (one wave)
    const int b = q >> 13;
    const int il = q & (PP - 1);
    const float* bp = pts + (size_t)b * PP * 3;
    const int gbase = b * PP;

    const float px = bp[il * 3 + 0];
    const float py = bp[il * 3 + 1];
    const float pz = bp[il * 3 + 2];

    float d[KNN];
#pragma unroll
    for (int s = 0; s < KNN; ++s) d[s] = dist[q * KNN + s];
    float d1 = d[0];
#pragma unroll
    for (int s = 1; s < KNN; ++s) d1 = fminf(d1, d[s]);
    const float thresh = 4.0f * d1;                // FILTER_SCALE * d1 * 2

    float num = 0.f, den = 0.f;
#pragma unroll
    for (int s = 0; s < KNN; ++s) {
        float w = phi[q * KNN + s] * nw[q * KNN + s];
        if (d[s] > thresh) w = 0.f;                // ball-query mask
        const int j = idx[q * KNN + s];
        const float nx = n2[(gbase + j) * 3 + 0];
        const float ny = n2[(gbase + j) * 3 + 1];
        const float nz = n2[(gbase + j) * 3 + 2];
        const float dts = (bp[j * 3 + 0] - px) * nx +
                          (bp[j * 3 + 1] - py) * ny +
                          (bp[j * 3 + 2] - pz) * nz;
        num += dts * dts * w;
        den += w;
    }
    const float dd = (den < EPSV) ? EPSV : den;
    float loss = num / dd;

#pragma unroll
    for (int off = 32; off >= 1; off >>= 1) loss += __shfl_down(loss, off, 64);
    if (threadIdx.x == 0) partial[blockIdx.x] = loss;
}

// ---- K5: final mean ---------------------------------------------------------
__global__ void finalize_kernel(const float* __restrict__ partial,
                                float* __restrict__ out) {
    // 64 threads, 256 partials
    float v = partial[threadIdx.x] + partial[threadIdx.x + 64] +
              partial[threadIdx.x + 128] + partial[threadIdx.x + 192];
#pragma unroll
    for (int off = 32; off >= 1; off >>= 1) v += __shfl_down(v, off, 64);
    if (threadIdx.x == 0) out[0] = v / (float)NPTS;
}

// ---- launch -----------------------------------------------------------------
extern "C" void kernel_launch(void* const* d_in, const int* in_sizes, int n_in,
                              void* d_out, int out_size, void* d_ws, size_t ws_size,
                              hipStream_t stream) {
    const float* points  = (const float*)d_in[0];   // (2, 8192, 3) f32
    const float* normals = (const float*)d_in[1];   // (2, 8192, 3) f32
    float* out = (float*)d_out;                     // scalar f32

    // workspace layout (floats): idx | dist | phi | nw | n1 | n2 | partials
    float* wsf    = (float*)d_ws;
    int*   w_idx  = (int*)wsf;                      // 16384*16 ints
    float* w_dist = wsf + 262144;                   // 16384*16
    float* w_phi  = wsf + 524288;                   // 16384*16
    float* w_nw   = wsf + 786432;                   // 16384*16
    float* w_n1   = wsf + 1048576;                  // 16384*3
    float* w_n2   = wsf + 1097728;                  // 16384*3
    float* w_part = wsf + 1146880;                  // 256

    knn_fused_kernel<<<NPTS / QPB, TPB, 0, stream>>>(points, normals,
                                                     w_idx, w_dist, w_phi, w_n1);
    denoise2_kernel<<<NPTS / 256, 256, 0, stream>>>(w_idx, w_phi, w_n1, w_nw, w_n2);
    loss_kernel<<<NPTS / 64, 64, 0, stream>>>(points, w_idx, w_dist, w_phi, w_nw, w_n2, w_part);
    finalize_kernel<<<1, 64, 0, stream>>>(w_part, out);
}